// Round 3
// baseline (650.340 us; speedup 1.0000x reference)
//
#include <hip/hip_runtime.h>
#include <hip/hip_bf16.h>
#include <math.h>

// ---------------------------------------------------------------------------
// CRGainHopLayerAnnealed: n=8192, in_dim=256, out_dim=128, d_sub=64, K1=3
// 7 dispatches:
//  1. hp_kernel   : Hp = H @ Wout^T  (+ bf16 transposed HpT from registers)
//  2. zgram       : Z_k = hop_k @ W_k^T  (+ per-block partial Gram)
//  3. gemm_tile   : P_k = Wout @ W_k^T
//  4. fused_big   : blocks 0-2 smallk (logdet series + Newton-Schulz inverse)
//                   blocks 3+  split-K bf16 MFMA Pbuf[s] = (L @ Hp) partial
//                   (double-buffered LDS, depth-2 register prefetch, 1 barrier)
//  5. small_w     : softmax weights + tail outputs
//  6. gemm_tile   : QT_k = s_k * P_k @ Minv_k   (Minv symmetric)
//  7. pre_finish  : out = LN(softthresh(Hp + Z@QT^T - 0.15*sum_s Pbuf[s]))
// ---------------------------------------------------------------------------

#define COEFF 0.03125f        // d/(n*eps^2) = 64/(8192*0.25)
#define SCL_LAP (-0.15f)      // -ETA*LAMBDA_LAP

typedef __attribute__((ext_vector_type(8))) short short8;
typedef __attribute__((ext_vector_type(4))) float f32x4;

__device__ __forceinline__ unsigned short f2bf_bits(float f) {
  unsigned int u = __float_as_uint(f);
  unsigned int r = (u + 0x7fffu + ((u >> 16) & 1u)) >> 16;   // RNE
  return (unsigned short)r;
}

// ---------------- generic tiled GEMM (small ops: Pb, QT) -------------------
// BM=BN=64, BK=16, 256 thr, 4x4 micro, k-major LDS. transB=1: C=A*B^T
__global__ __launch_bounds__(256) void gemm_tile(
    const float* __restrict__ A, const float* __restrict__ B,
    float* __restrict__ C, const float* __restrict__ scale_ptr,
    int K, int lda, int ldb, int ldc,
    long sA, long sB, long sC, int transB) {
  __shared__ __align__(16) float As[16][68];
  __shared__ __align__(16) float Bs[16][68];
  const int tid = threadIdx.x;
  const int tx = tid & 15, ty = tid >> 4;
  const int m0 = blockIdx.y * 64, n0 = blockIdx.x * 64;
  const int b = blockIdx.z;
  A += (size_t)b * sA; B += (size_t)b * sB; C += (size_t)b * sC;
  float cc[4][4];
#pragma unroll
  for (int i = 0; i < 4; ++i)
#pragma unroll
    for (int j = 0; j < 4; ++j) cc[i][j] = 0.f;
  const int lr = tid >> 2, lc = (tid & 3) << 2;
  for (int k0 = 0; k0 < K; k0 += 16) {
    float4 av = *(const float4*)(A + (size_t)(m0 + lr) * lda + k0 + lc);
    As[lc][lr] = av.x; As[lc + 1][lr] = av.y; As[lc + 2][lr] = av.z; As[lc + 3][lr] = av.w;
    if (transB) {
      float4 bv = *(const float4*)(B + (size_t)(n0 + lr) * ldb + k0 + lc);
      Bs[lc][lr] = bv.x; Bs[lc + 1][lr] = bv.y; Bs[lc + 2][lr] = bv.z; Bs[lc + 3][lr] = bv.w;
    } else {
      int kk = tid & 15, n4 = (tid >> 4) << 2;
      float4 bv = *(const float4*)(B + (size_t)(k0 + kk) * ldb + n0 + n4);
      *(float4*)&Bs[kk][n4] = bv;
    }
    __syncthreads();
#pragma unroll
    for (int kk = 0; kk < 16; ++kk) {
      float4 a4 = *(const float4*)&As[kk][ty * 4];
      float4 b4 = *(const float4*)&Bs[kk][tx * 4];
      float a[4] = {a4.x, a4.y, a4.z, a4.w};
      float bb[4] = {b4.x, b4.y, b4.z, b4.w};
#pragma unroll
      for (int i = 0; i < 4; ++i)
#pragma unroll
        for (int j = 0; j < 4; ++j) cc[i][j] = fmaf(a[i], bb[j], cc[i][j]);
    }
    __syncthreads();
  }
  float scale = scale_ptr ? scale_ptr[b] : 1.0f;
#pragma unroll
  for (int i = 0; i < 4; ++i)
#pragma unroll
    for (int j = 0; j < 4; ++j)
      C[(size_t)(m0 + ty * 4 + i) * ldc + n0 + tx * 4 + j] = cc[i][j] * scale;
}

// ---------------- Hp = H @ Wout^T, writes Hp fp32 + HpT bf16 ---------------
__global__ __launch_bounds__(256) void hp_kernel(
    const float* __restrict__ H, const float* __restrict__ Wout,
    float* __restrict__ Hp, unsigned short* __restrict__ HpT) {
  __shared__ __align__(16) float As[16][68];
  __shared__ __align__(16) float Bs[16][68];
  const int tid = threadIdx.x;
  const int tx = tid & 15, ty = tid >> 4;
  const int m0 = blockIdx.y * 64, n0 = blockIdx.x * 64;
  float cc[4][4];
#pragma unroll
  for (int i = 0; i < 4; ++i)
#pragma unroll
    for (int j = 0; j < 4; ++j) cc[i][j] = 0.f;
  const int lr = tid >> 2, lc = (tid & 3) << 2;
  for (int k0 = 0; k0 < 256; k0 += 16) {
    float4 av = *(const float4*)(H + (size_t)(m0 + lr) * 256 + k0 + lc);
    As[lc][lr] = av.x; As[lc + 1][lr] = av.y; As[lc + 2][lr] = av.z; As[lc + 3][lr] = av.w;
    float4 bv = *(const float4*)(Wout + (size_t)(n0 + lr) * 256 + k0 + lc);
    Bs[lc][lr] = bv.x; Bs[lc + 1][lr] = bv.y; Bs[lc + 2][lr] = bv.z; Bs[lc + 3][lr] = bv.w;
    __syncthreads();
#pragma unroll
    for (int kk = 0; kk < 16; ++kk) {
      float4 a4 = *(const float4*)&As[kk][ty * 4];
      float4 b4 = *(const float4*)&Bs[kk][tx * 4];
      float a[4] = {a4.x, a4.y, a4.z, a4.w};
      float bb[4] = {b4.x, b4.y, b4.z, b4.w};
#pragma unroll
      for (int i = 0; i < 4; ++i)
#pragma unroll
        for (int j = 0; j < 4; ++j) cc[i][j] = fmaf(a[i], bb[j], cc[i][j]);
    }
    __syncthreads();
  }
#pragma unroll
  for (int i = 0; i < 4; ++i)
    *(float4*)(Hp + (size_t)(m0 + ty * 4 + i) * 128 + n0 + tx * 4) =
        (float4){cc[i][0], cc[i][1], cc[i][2], cc[i][3]};
#pragma unroll
  for (int j = 0; j < 4; ++j) {
    ushort4 u;
    u.x = f2bf_bits(cc[0][j]); u.y = f2bf_bits(cc[1][j]);
    u.z = f2bf_bits(cc[2][j]); u.w = f2bf_bits(cc[3][j]);
    *(ushort4*)(HpT + (size_t)(n0 + tx * 4 + j) * 8192 + m0 + ty * 4) = u;
  }
}

// ---------------- Z_k = hop_k @ W_k^T + per-block partial Gram -------------
// grid (128, 3): 64 rows per block; Gpart[k*128+bx] = Ztile^T Ztile
__global__ __launch_bounds__(256) void zgram(
    const float* __restrict__ hop, const float* __restrict__ Wst,
    float* __restrict__ Zbuf, float* __restrict__ Gpart) {
  __shared__ __align__(16) float sm[4352];
  float (*As)[68] = (float(*)[68])sm;          // 16x68
  float (*Bs)[68] = (float(*)[68])(sm + 1088); // 16x68
  float (*Zs)[68] = (float(*)[68])sm;          // 64x68 (aliases, used after)
  const int tid = threadIdx.x;
  const int tx = tid & 15, ty = tid >> 4;
  const int m0 = blockIdx.x * 64, k = blockIdx.y;
  const float* A = hop + (size_t)k * 2097152;
  const float* B = Wst + (size_t)k * 16384;
  float cc[4][4];
#pragma unroll
  for (int i = 0; i < 4; ++i)
#pragma unroll
    for (int j = 0; j < 4; ++j) cc[i][j] = 0.f;
  const int lr = tid >> 2, lc = (tid & 3) << 2;
  for (int k0 = 0; k0 < 256; k0 += 16) {
    float4 av = *(const float4*)(A + (size_t)(m0 + lr) * 256 + k0 + lc);
    As[lc][lr] = av.x; As[lc + 1][lr] = av.y; As[lc + 2][lr] = av.z; As[lc + 3][lr] = av.w;
    float4 bv = *(const float4*)(B + (size_t)lr * 256 + k0 + lc);
    Bs[lc][lr] = bv.x; Bs[lc + 1][lr] = bv.y; Bs[lc + 2][lr] = bv.z; Bs[lc + 3][lr] = bv.w;
    __syncthreads();
#pragma unroll
    for (int kk = 0; kk < 16; ++kk) {
      float4 a4 = *(const float4*)&As[kk][ty * 4];
      float4 b4 = *(const float4*)&Bs[kk][tx * 4];
      float a[4] = {a4.x, a4.y, a4.z, a4.w};
      float bb[4] = {b4.x, b4.y, b4.z, b4.w};
#pragma unroll
      for (int i = 0; i < 4; ++i)
#pragma unroll
        for (int j = 0; j < 4; ++j) cc[i][j] = fmaf(a[i], bb[j], cc[i][j]);
    }
    __syncthreads();
  }
  // write Z and stage tile into LDS for the partial Gram
#pragma unroll
  for (int i = 0; i < 4; ++i) {
    float4 v = {cc[i][0], cc[i][1], cc[i][2], cc[i][3]};
    *(float4*)(Zbuf + (size_t)(m0 + ty * 4 + i) * 192 + k * 64 + tx * 4) = v;
    *(float4*)&Zs[ty * 4 + i][tx * 4] = v;
  }
  __syncthreads();
  const int d0 = (tid & 15) * 4, e0 = (tid >> 4) * 4;
  float acc[4][4];
#pragma unroll
  for (int i = 0; i < 4; ++i)
#pragma unroll
    for (int j = 0; j < 4; ++j) acc[i][j] = 0.f;
  for (int rr = 0; rr < 64; ++rr) {
    float4 zd4 = *(const float4*)&Zs[rr][d0];
    float4 ze4 = *(const float4*)&Zs[rr][e0];
    float zd[4] = {zd4.x, zd4.y, zd4.z, zd4.w};
    float ze[4] = {ze4.x, ze4.y, ze4.z, ze4.w};
#pragma unroll
    for (int i = 0; i < 4; ++i)
#pragma unroll
      for (int j = 0; j < 4; ++j) acc[i][j] = fmaf(zd[i], ze[j], acc[i][j]);
  }
  float* g = Gpart + (size_t)(k * 128 + blockIdx.x) * 4096;
#pragma unroll
  for (int i = 0; i < 4; ++i)
    *(float4*)(g + (d0 + i) * 64 + e0) = (float4){acc[i][0], acc[i][1], acc[i][2], acc[i][3]};
}

// ---------------- fused-dispatch helpers (256 threads) ---------------------
__device__ __forceinline__ float blocksum256(float v, volatile float* scr) {
#pragma unroll
  for (int o = 32; o; o >>= 1) v += __shfl_xor(v, o);
  __syncthreads();
  if ((threadIdx.x & 63) == 0) scr[threadIdx.x >> 6] = v;
  __syncthreads();
  return scr[0] + scr[1] + scr[2] + scr[3];
}

// C = X * Y for 64x64 with X symmetric (reads X "rows" via symmetry): b128 only
__device__ __forceinline__ void gemm64s(const float* X, const float* Y,
                                        float acc[4][4]) {
  const int tx = threadIdx.x & 15, ty = threadIdx.x >> 4;
#pragma unroll
  for (int i = 0; i < 4; ++i)
#pragma unroll
    for (int j = 0; j < 4; ++j) acc[i][j] = 0.f;
  for (int kk = 0; kk < 64; ++kk) {
    float4 a4 = *(const float4*)&X[kk * 64 + ty * 4];
    float4 b4 = *(const float4*)&Y[kk * 64 + tx * 4];
    float a[4] = {a4.x, a4.y, a4.z, a4.w};
    float bb[4] = {b4.x, b4.y, b4.z, b4.w};
#pragma unroll
    for (int i = 0; i < 4; ++i)
#pragma unroll
      for (int j = 0; j < 4; ++j) acc[i][j] = fmaf(a[i], bb[j], acc[i][j]);
  }
}

__device__ __forceinline__ void wb64(float* D, const float acc[4][4]) {
  const int tx = threadIdx.x & 15, ty = threadIdx.x >> 4;
#pragma unroll
  for (int i = 0; i < 4; ++i)
#pragma unroll
    for (int j = 0; j < 4; ++j) D[(ty * 4 + i) * 64 + tx * 4 + j] = acc[i][j];
}

__device__ __forceinline__ float dot64(const float* X, const float* Y, float* scr) {
  const int tx = threadIdx.x & 15, ty = threadIdx.x >> 4;
  float v = 0.f;
#pragma unroll
  for (int i = 0; i < 4; ++i)
#pragma unroll
    for (int j = 0; j < 4; ++j) {
      int idx = (ty * 4 + i) * 64 + tx * 4 + j;
      v += X[idx] * Y[idx];
    }
  return blocksum256(v, scr);
}

// ---------------- fused: split-K bf16 MFMA L@Hp  +  smallk -----------------
// grid 515. blocks 0-2: smallk(k=bid). blocks 3-514: GEMM (BM=128,BK=32).
__global__ __launch_bounds__(256) void fused_big(
    const float* __restrict__ Lp, const unsigned short* __restrict__ HpT,
    float* __restrict__ Pbuf, const float* __restrict__ Gpart,
    float* __restrict__ Minv, float* __restrict__ Rout) {
  __shared__ __align__(16) float smem[12304];
  const int tid = threadIdx.x;

  if (blockIdx.x >= 3) {
    // ------------- big GEMM: double-buffered LDS, depth-2 prefetch ---------
    unsigned short* sm = (unsigned short*)smem;
    // As[b]: sm + b*5120 ([128][40]); Bs[b]: sm + 10240 + b*5120
    const int g = blockIdx.x - 3;
    const int m0 = (g & 63) * 128;
    const int kbase = (g >> 6) * 1024;
    const int wave = tid >> 6, lane = tid & 63;
    const int ar = tid >> 1, ah = (tid & 1) * 16;
    const size_t lrow = (size_t)(m0 + ar) * 8192;
    const size_t brow = (size_t)ar * 8192;
    f32x4 acc[2][8];
#pragma unroll
    for (int i = 0; i < 2; ++i)
#pragma unroll
      for (int j = 0; j < 8; ++j) acc[i][j] = (f32x4){0.f, 0.f, 0.f, 0.f};
    float4 apf[2][4];
    uint4 bpf[2][2];
#pragma unroll
    for (int p = 0; p < 2; ++p) {
      const float* ap = Lp + lrow + kbase + p * 32 + ah;
      apf[p][0] = *(const float4*)(ap); apf[p][1] = *(const float4*)(ap + 4);
      apf[p][2] = *(const float4*)(ap + 8); apf[p][3] = *(const float4*)(ap + 12);
      const unsigned short* bp = HpT + brow + kbase + p * 32 + ah;
      bpf[p][0] = *(const uint4*)(bp); bpf[p][1] = *(const uint4*)(bp + 8);
    }
    const int quad = lane >> 4, mcol = lane & 15;
    for (int step = 0; step < 32; ++step) {
      const int b = step & 1;
      unsigned short (*As)[40] = (unsigned short(*)[40])(sm + b * 5120);
      unsigned short (*Bs)[40] = (unsigned short(*)[40])(sm + 10240 + b * 5120);
      {
        __attribute__((aligned(16))) unsigned short tmp[16];
        const float* f = (const float*)apf[b];
#pragma unroll
        for (int i = 0; i < 16; ++i) tmp[i] = f2bf_bits(f[i]);
        *(uint4*)&As[ar][ah] = *(const uint4*)&tmp[0];
        *(uint4*)&As[ar][ah + 8] = *(const uint4*)&tmp[8];
        *(uint4*)&Bs[ar][ah] = bpf[b][0];
        *(uint4*)&Bs[ar][ah + 8] = bpf[b][1];
      }
      if (step < 30) {  // prefetch tile step+2 (2-step distance)
        int kc = kbase + (step + 2) * 32;
        const float* ap = Lp + lrow + kc + ah;
        apf[b][0] = *(const float4*)(ap); apf[b][1] = *(const float4*)(ap + 4);
        apf[b][2] = *(const float4*)(ap + 8); apf[b][3] = *(const float4*)(ap + 12);
        const unsigned short* bp = HpT + brow + kc + ah;
        bpf[b][0] = *(const uint4*)(bp); bpf[b][1] = *(const uint4*)(bp + 8);
      }
      __syncthreads();
      short8 af0 = *(const short8*)&As[wave * 32 + mcol][quad * 8];
      short8 af1 = *(const short8*)&As[wave * 32 + 16 + mcol][quad * 8];
#pragma unroll
      for (int nt = 0; nt < 8; ++nt) {
        short8 bf = *(const short8*)&Bs[nt * 16 + mcol][quad * 8];
        acc[0][nt] = __builtin_amdgcn_mfma_f32_16x16x32_bf16(af0, bf, acc[0][nt], 0, 0, 0);
        acc[1][nt] = __builtin_amdgcn_mfma_f32_16x16x32_bf16(af1, bf, acc[1][nt], 0, 0, 0);
      }
    }
    float* P = Pbuf + (size_t)(g >> 6) * 1048576;
#pragma unroll
    for (int mt = 0; mt < 2; ++mt)
#pragma unroll
      for (int nt = 0; nt < 8; ++nt)
#pragma unroll
        for (int r = 0; r < 4; ++r) {
          int grow = m0 + wave * 32 + mt * 16 + quad * 4 + r;
          int gcol = nt * 16 + mcol;
          P[(size_t)grow * 128 + gcol] = acc[mt][nt][r];
        }
    return;
  }

  // ---------------- smallk path: k = blockIdx.x ----------------------------
  const int k = blockIdx.x;
  float* B0 = smem;          // E
  float* B1 = smem + 4096;   // E2 -> X
  float* B2 = smem + 8192;   // E3 -> T
  float* scr = smem + 12288;
  // M = I + coeff * sum_b Gpart[k][b]   (128 partials, float4 reduce)
  {
    const float* gp = Gpart + (size_t)k * 524288 + tid * 16;
    float4 s0 = {0,0,0,0}, s1 = {0,0,0,0}, s2 = {0,0,0,0}, s3 = {0,0,0,0};
    for (int b = 0; b < 128; ++b) {
      const float4* p = (const float4*)(gp + (size_t)b * 4096);
      s0.x += p[0].x; s0.y += p[0].y; s0.z += p[0].z; s0.w += p[0].w;
      s1.x += p[1].x; s1.y += p[1].y; s1.z += p[1].z; s1.w += p[1].w;
      s2.x += p[2].x; s2.y += p[2].y; s2.z += p[2].z; s2.w += p[2].w;
      s3.x += p[3].x; s3.y += p[3].y; s3.z += p[3].z; s3.w += p[3].w;
    }
    float vals[16] = {s0.x, s0.y, s0.z, s0.w, s1.x, s1.y, s1.z, s1.w,
                      s2.x, s2.y, s2.z, s2.w, s3.x, s3.y, s3.z, s3.w};
#pragma unroll
    for (int t = 0; t < 16; ++t) {
      int i = tid * 16 + t;
      B0[i] = COEFF * vals[t] + ((i >> 6) == (i & 63) ? 1.f : 0.f);
    }
  }
  __syncthreads();
  // Gershgorin bounds (wave 0; M symmetric)
  if (tid < 64) {
    float rs = 0.f, dg = B0[tid * 65];
    for (int j = 0; j < 64; ++j) rs += fabsf(B0[j * 64 + tid]);
    float lo = 2.f * dg - rs, hi = rs;
#pragma unroll
    for (int o = 32; o; o >>= 1) {
      lo = fminf(lo, __shfl_xor(lo, o));
      hi = fmaxf(hi, __shfl_xor(hi, o));
    }
    if (tid == 0) scr[4] = 0.5f * (fmaxf(lo, 1.f) + hi);
  }
  __syncthreads();
  const float alpha = scr[4], inva = 1.f / alpha;
  for (int i = tid; i < 4096; i += 256) {
    int r = i >> 6, c = i & 63;
    B0[i] = B0[i] * inva - (r == c ? 1.f : 0.f);   // E
  }
  __syncthreads();
  const int tx = tid & 15, ty = tid >> 4;
  float v1 = 0.f, v2 = 0.f;
#pragma unroll
  for (int i = 0; i < 4; ++i)
#pragma unroll
    for (int j = 0; j < 4; ++j) {
      int r = ty * 4 + i, c = tx * 4 + j;
      float e = B0[r * 64 + c];
      if (r == c) v1 += e;
      v2 += e * e;
    }
  float t1 = blocksum256(v1, scr);
  float t2 = blocksum256(v2, scr);
  float acc[4][4];
  gemm64s(B0, B0, acc); __syncthreads(); wb64(B1, acc); __syncthreads();  // E2
  float t3 = dot64(B1, B0, scr);
  float t4 = dot64(B1, B1, scr);
  gemm64s(B1, B0, acc); __syncthreads(); wb64(B2, acc); __syncthreads();  // E3
  float t5 = dot64(B2, B1, scr);
  float t6 = dot64(B2, B2, scr);
  gemm64s(B1, B1, acc);                                                   // E4 (regs)
  {
    float v7 = 0.f, v8 = 0.f;
#pragma unroll
    for (int i = 0; i < 4; ++i)
#pragma unroll
      for (int j = 0; j < 4; ++j) {
        int idx = (ty * 4 + i) * 64 + tx * 4 + j;
        v7 += acc[i][j] * B2[idx];
        v8 += acc[i][j] * acc[i][j];
      }
    float t7 = blocksum256(v7, scr);
    float t8 = blocksum256(v8, scr);
    if (tid == 0) {
      float ld = 64.f * logf(alpha) + t1 - t2 * 0.5f + t3 / 3.f - t4 * 0.25f
                 + t5 * 0.2f - t6 / 6.f + t7 / 7.f - t8 * 0.125f;
      Rout[k] = 0.5f * ld;
    }
  }
  // Newton-Schulz: X0 = I - E ; X <- X(2I - (I+E)X), 2 iters
  for (int i = tid; i < 4096; i += 256) {
    int r = i >> 6, c = i & 63;
    B1[i] = (r == c ? 1.f : 0.f) - B0[i];
  }
  __syncthreads();
  for (int it = 0; it < 2; ++it) {
    gemm64s(B0, B1, acc);       // E*X
    __syncthreads();
#pragma unroll
    for (int i = 0; i < 4; ++i)
#pragma unroll
      for (int j = 0; j < 4; ++j) {
        int idx = (ty * 4 + i) * 64 + tx * 4 + j;
        B2[idx] = acc[i][j] + B1[idx];       // T = E*X + X
      }
    __syncthreads();
    gemm64s(B1, B2, acc);       // X*T
    __syncthreads();
#pragma unroll
    for (int i = 0; i < 4; ++i)
#pragma unroll
      for (int j = 0; j < 4; ++j) {
        int idx = (ty * 4 + i) * 64 + tx * 4 + j;
        B1[idx] = 2.f * B1[idx] - acc[i][j]; // X = 2X - X*T
      }
    __syncthreads();
  }
  for (int i = tid; i < 4096; i += 256) Minv[k * 4096 + i] = B1[i] * inva;
}

// ---------------- weights / tail outputs -----------------------------------
__global__ void small_w(const float* __restrict__ R, const float* __restrict__ tauP,
                        float* __restrict__ tail, float* __restrict__ sb) {
  if (threadIdx.x != 0) return;
  float R0 = R[0], R1 = R[1], R2 = R[2];
  float d0 = R0, d1 = R1 - R0, d2 = R2 - R1;
  float mean = (d0 + d1 + d2) * (1.f / 3.f);
  float e0 = d0 - mean, e1 = d1 - mean, e2 = d2 - mean;
  float sd = sqrtf((e0 * e0 + e1 * e1 + e2 * e2) * 0.5f) + 1e-6f;
  float n0 = e0 / sd, n1 = e1 / sd, n2 = e2 / sd;
  float tau = tauP[0];
  float x0 = n0 / tau, x1 = n1 / tau, x2 = n2 / tau;
  float mx = fmaxf(x0, fmaxf(x1, x2));
  float w0 = expf(x0 - mx), w1 = expf(x1 - mx), w2 = expf(x2 - mx);
  float s = w0 + w1 + w2;
  w0 /= s; w1 /= s; w2 /= s;
  tail[0] = w0; tail[1] = w1; tail[2] = w2;
  tail[3] = n0; tail[4] = n1; tail[5] = n2;
  tail[6] = d0; tail[7] = d1; tail[8] = d2;
  sb[0] = 0.015625f * w0; sb[1] = 0.015625f * w1; sb[2] = 0.015625f * w2;  // ETA*coeff*w
}

// ---------------- pre + split-K reduce + softthresh + LayerNorm ------------
// grid 256: 32 rows x 128 cols per block. pre = Z@QT^T + Hp - 0.15*sum Pbuf
__global__ __launch_bounds__(256) void pre_finish(
    const float* __restrict__ Zb, const float* __restrict__ QT,
    const float* __restrict__ Hp, const float* __restrict__ Pbuf,
    const float* __restrict__ thr, const float* __restrict__ gamma,
    const float* __restrict__ beta, float* __restrict__ out) {
  __shared__ __align__(16) float As[16][36];
  __shared__ __align__(16) float Bs[16][132];
  const int tid = threadIdx.x;
  const int tx = tid & 31, ty = tid >> 5;   // tx: col/4, ty: row/4
  const int m0 = blockIdx.x * 32;
  float cc[4][4];
#pragma unroll
  for (int i = 0; i < 4; ++i)
#pragma unroll
    for (int j = 0; j < 4; ++j) cc[i][j] = 0.f;
  for (int k0 = 0; k0 < 192; k0 += 16) {
    if (tid < 128) {
      int row = tid >> 2, c4 = (tid & 3) * 4;
      float4 v = *(const float4*)(Zb + (size_t)(m0 + row) * 192 + k0 + c4);
      As[c4][row] = v.x; As[c4 + 1][row] = v.y; As[c4 + 2][row] = v.z; As[c4 + 3][row] = v.w;
    }
#pragma unroll
    for (int t = 0; t < 2; ++t) {
      int idx = tid + t * 256;
      int n = idx >> 2, c4 = (idx & 3) * 4;
      float4 v = *(const float4*)(QT + (size_t)n * 192 + k0 + c4);
      Bs[c4][n] = v.x; Bs[c4 + 1][n] = v.y; Bs[c4 + 2][n] = v.z; Bs[c4 + 3][n] = v.w;
    }
    __syncthreads();
#pragma unroll
    for (int kk = 0; kk < 16; ++kk) {
      float4 a4 = *(const float4*)&As[kk][ty * 4];
      float4 b4 = *(const float4*)&Bs[kk][tx * 4];
      float a[4] = {a4.x, a4.y, a4.z, a4.w};
      float bb[4] = {b4.x, b4.y, b4.z, b4.w};
#pragma unroll
      for (int i = 0; i < 4; ++i)
#pragma unroll
        for (int j = 0; j < 4; ++j) cc[i][j] = fmaf(a[i], bb[j], cc[i][j]);
    }
    __syncthreads();
  }
  // epilogue: rows r = m0+ty*4+i, cols c = tx*4+j
  float4 tv = *(const float4*)(thr + tx * 4);
  float tj[4] = {fabsf(tv.x), fabsf(tv.y), fabsf(tv.z), fabsf(tv.w)};
  float sth[4][4], rs[4];
#pragma unroll
  for (int i = 0; i < 4; ++i) {
    const size_t off = (size_t)(m0 + ty * 4 + i) * 128 + tx * 4;
    float4 h = *(const float4*)(Hp + off);
    float x[4] = {h.x, h.y, h.z, h.w};
    float4 l0 = {0, 0, 0, 0};
#pragma unroll
    for (int s = 0; s < 8; ++s) {
      float4 p = *(const float4*)(Pbuf + (size_t)s * 1048576 + off);
      l0.x += p.x; l0.y += p.y; l0.z += p.z; l0.w += p.w;
    }
    x[0] += cc[i][0] + SCL_LAP * l0.x;
    x[1] += cc[i][1] + SCL_LAP * l0.y;
    x[2] += cc[i][2] + SCL_LAP * l0.z;
    x[3] += cc[i][3] + SCL_LAP * l0.w;
    float lsum = 0.f;
#pragma unroll
    for (int j = 0; j < 4; ++j) {
      float a = fmaxf(fabsf(x[j]) - tj[j], 0.f);
      sth[i][j] = (x[j] >= 0.f) ? a : -a;
      lsum += sth[i][j];
    }
    rs[i] = lsum;
  }
  // reduce over the 32 tx lanes (bits 0..4 of lane id)
#pragma unroll
  for (int o = 16; o; o >>= 1)
#pragma unroll
    for (int i = 0; i < 4; ++i) rs[i] += __shfl_xor(rs[i], o);
  float var[4];
#pragma unroll
  for (int i = 0; i < 4; ++i) {
    float mean = rs[i] * (1.f / 128.f);
    float v = 0.f;
#pragma unroll
    for (int j = 0; j < 4; ++j) {
      sth[i][j] -= mean;
      v += sth[i][j] * sth[i][j];
    }
    var[i] = v;
  }
#pragma unroll
  for (int o = 16; o; o >>= 1)
#pragma unroll
    for (int i = 0; i < 4; ++i) var[i] += __shfl_xor(var[i], o);
  float4 gv = *(const float4*)(gamma + tx * 4);
  float4 bv = *(const float4*)(beta + tx * 4);
  float gj[4] = {gv.x, gv.y, gv.z, gv.w};
  float bj[4] = {bv.x, bv.y, bv.z, bv.w};
#pragma unroll
  for (int i = 0; i < 4; ++i) {
    float inv = rsqrtf(var[i] * (1.f / 128.f) + 1e-5f);
    float4 o4;
    o4.x = sth[i][0] * inv * gj[0] + bj[0];
    o4.y = sth[i][1] * inv * gj[1] + bj[1];
    o4.z = sth[i][2] * inv * gj[2] + bj[2];
    o4.w = sth[i][3] * inv * gj[3] + bj[3];
    *(float4*)(out + (size_t)(m0 + ty * 4 + i) * 128 + tx * 4) = o4;
  }
}

// ---------------------------------------------------------------------------
extern "C" void kernel_launch(void* const* d_in, const int* in_sizes, int n_in,
                              void* d_out, int out_size, void* d_ws, size_t ws_size,
                              hipStream_t stream) {
  const float* H = (const float*)d_in[0];
  const float* hop = (const float*)d_in[1];
  const float* L = (const float*)d_in[2];
  const float* Wst = (const float*)d_in[3];
  const float* Wout = (const float*)d_in[4];
  const float* thr = (const float*)d_in[5];
  const float* gamma = (const float*)d_in[6];
  const float* beta = (const float*)d_in[7];
  const float* tau = (const float*)d_in[8];
  float* out = (float*)d_out;

  float* ws = (float*)d_ws;
  float* Zbuf = ws;                       // [8192][192] packed Z (k*64+d)
  float* Hp = Zbuf + 1572864;             // [8192][128]
  float* Gpart = Hp + 1048576;            // [3][128][4096]
  float* Minv = Gpart + 1572864;          // [3][64][64]
  float* Rb = Minv + 12288;               // [3]
  float* sb = Rb + 16;                    // [3]
  float* Pb = sb + 16;                    // [3][128][64]
  float* QT = Pb + 24576;                 // [128][192] packed QT
  float* Pbuf = QT + 24576;               // [8][8192][128] split-K partials
  unsigned short* HpT = (unsigned short*)(Pbuf + 8388608);  // [128][8192] bf16

  // 1. Hp = H @ Wout^T  (+ HpT bf16)
  hp_kernel<<<dim3(2, 128), 256, 0, stream>>>(H, Wout, Hp, HpT);
  // 2. Z_k + partial Grams
  zgram<<<dim3(128, 3), 256, 0, stream>>>(hop, Wst, Zbuf, Gpart);
  // 3. P_k = Wout @ W_k^T
  gemm_tile<<<dim3(1, 2, 3), 256, 0, stream>>>(
      Wout, Wst, Pb, nullptr, 256, 256, 256, 64, 0L, 16384L, 8192L, 1);
  // 4. fused: smallk (blocks 0-2) + split-K L@Hp partials (blocks 3-514)
  fused_big<<<dim3(515), 256, 0, stream>>>(L, HpT, Pbuf, Gpart, Minv, Rb);
  // 5. weights + tail outputs
  small_w<<<dim3(1), 64, 0, stream>>>(Rb, tau, out + 1048576, sb);
  // 6. QT_k = s_k * P_k @ Minv_k (Minv symmetric)
  gemm_tile<<<dim3(1, 2, 3), 256, 0, stream>>>(
      Pb, Minv, QT, sb, 64, 64, 64, 192, 8192L, 4096L, 64L, 0);
  // 7. pre + reduce + softthresh + LN
  pre_finish<<<dim3(256), 256, 0, stream>>>(Zbuf, QT, Hp, Pbuf, thr, gamma, beta, out);

  (void)in_sizes; (void)n_in; (void)out_size; (void)ws_size;
}